// Round 17
// baseline (581.316 us; speedup 1.0000x reference)
//
#include <hip/hip_runtime.h>
#include <cstdint>

#define Tn 200
#define En 512

// out[t][g] = (relu?)( A[t][:512] . W[g][:512] + bp1[g] + bp2?[g] )
// If ids!=nullptr, row t of A is tab[ids[63*Tn+t]] (fused embed gather).
__global__ __launch_bounds__(256) void gemm_rows(const float* __restrict__ A,
                                                 const int* __restrict__ ids,
                                                 const float* __restrict__ tab,
                                                 const float* __restrict__ W,
                                                 const float* __restrict__ bp1,
                                                 const float* __restrict__ bp2,
                                                 float* __restrict__ out,
                                                 int G, int relu) {
  __shared__ float xl[8 * 512];
  const int gr = blockIdx.x * 256 + threadIdx.x;
  const int t0 = blockIdx.y * 8;
  if (ids) {
    // embed-fused staging: 32 threads per row, float4 each
    const int r = threadIdx.x >> 5, e = threadIdx.x & 31;
    const long id = ids[63 * Tn + t0 + r];
    const float4* src = (const float4*)(tab + (size_t)id * En);
    ((float4*)&xl[r * 512])[e] = src[e];
    ((float4*)&xl[r * 512])[e + 32] = src[e + 32];
    ((float4*)&xl[r * 512])[e + 64] = src[e + 64];
    ((float4*)&xl[r * 512])[e + 96] = src[e + 96];
  } else {
    for (int i = threadIdx.x; i < 8 * 512; i += 256) xl[i] = A[(size_t)t0 * 512 + i];
  }
  __syncthreads();
  const float b = bp1[gr] + (bp2 ? bp2[gr] : 0.f);
  float acc[8];
#pragma unroll
  for (int tt = 0; tt < 8; tt++) acc[tt] = b;
  const float4* wr = (const float4*)(W + (size_t)gr * 512);
  for (int k4 = 0; k4 < 128; k4++) {
    const float4 w = wr[k4];
#pragma unroll
    for (int tt = 0; tt < 8; tt++) {
      const float4 xv = *(const float4*)&xl[tt * 512 + k4 * 4];
      acc[tt] = fmaf(w.x, xv.x, fmaf(w.y, xv.y, fmaf(w.z, xv.z, fmaf(w.w, xv.w, acc[tt]))));
    }
  }
#pragma unroll
  for (int tt = 0; tt < 8; tt++) {
    float v = acc[tt];
    if (relu) v = fmaxf(v, 0.f);
    out[(size_t)(t0 + tt) * G + gr] = v;
  }
}

// ---- bidirectional LSTM recurrence: R16 structure + quad-polling ----
// Grid 128; workers b&7==0 (fwd) / ==1 (bwd); 16 WGs x 512 thr per domain,
// LDS pad -> 1 WG/CU. Agent/LLC exchange. Changes vs R16:
//  - QUAD-polling: 60 pollers/WG, each owns 4 adjacent slots probed by TWO
//    pipelined global_load_dwordx4 (one vmcnt wait -> same RT as one probe);
//    probe messages halve again (monotone win R13->R10->R15).
//  - NO memset dependency: layers alternate stamp ranges (t+1 vs 1e6+t+1)
//    and each layer rewrites every slot every launch, so a slot never holds
//    a stale stamp equal to the current target across graph replays.
__global__ __launch_bounds__(512, 2) void rec_k(const float* __restrict__ xp,   // [T][2048] fwd|bwd
                                                float* __restrict__ hcat,       // [T][512]
                                                unsigned long long* __restrict__ ex, // [T][512]
                                                const float* __restrict__ whh,  // dir-major 2*1024*256
                                                unsigned stampbase) {
  __shared__ __align__(16) float hs[2][288];  // stride-36 chunks, double buffer
  __shared__ float pad[21000];                // forces 1 WG/CU (>80KB total)
  const int b = blockIdx.x;
  const int dir = b & 7;
  if (dir > 1) return;                 // 32 worker blocks, 96 exit
  const int wg = b >> 3;               // 0..15
  const int tid = threadIdx.x;
  const int lane = tid & 63;
  const int row = tid >> 3, kc = tid & 7;
  const int elem = row >> 2, gate = row & 3;
  const int he = wg * 16 + elem;        // global h element [0,256)
  const int gr = gate * 256 + he;       // gate row (i|f|g|o blocks of 256)
  const float* whhD = whh + (size_t)dir * 262144;
  const float* xpD = xp + dir * 1024;

  if (stampbase == 0xDEADBEEFu) {  // never true at runtime; keeps pad live
    pad[tid] = xp[tid];
    hcat[tid] = pad[tid ^ 1];
  }

  float4 q0, q1, q2, q3, q4, q5, q6, q7;
  {
    const float4* p = (const float4*)(whhD + (size_t)gr * 256 + kc * 32);
    q0 = p[0]; q1 = p[1]; q2 = p[2]; q3 = p[3];
    q4 = p[4]; q5 = p[5]; q6 = p[6]; q7 = p[7];
  }
  for (int i = tid; i < 2 * 288; i += 512) ((float*)hs)[i] = 0.f;
  float c = 0.f;
  float xv = 0.f;
  if (kc == 0) xv = xpD[(size_t)(dir ? (Tn - 1) : 0) * 2048 + gr];
  const int isprod = ((lane & 31) == 0);   // tid%32==0: 16 producers
  const int base = lane & 32;
  // quad-poller mapping: rank among non-producers; first 60 ranks poll the
  // 60 remote slot-QUADS (own-WG 4 quads self-staged by producers).
  const int pr = tid - 1 - (tid >> 5);
  const int ispoll = (!isprod) && (pr < 60);
  const int quadIdx = ispoll ? (pr + (pr >= wg * 4 ? 4 : 0)) : 0;
  const int s0 = 4 * quadIdx;                          // first slot of quad
  const int coff4 = (s0 >> 5) * 36 + (s0 & 31);        // 4 floats, 16B-aligned
  const int poff = (he >> 5) * 36 + (he & 31);
  __syncthreads();  // init barrier (full drain, once)

  for (int t = 0; t < Tn; ++t) {
    const int p = t & 1;
    // matvec on hs[p] = h(t-1)
    const float4* h4 = (const float4*)&hs[p][kc * 36];
    const float4 h0 = h4[0], h1 = h4[1], h2 = h4[2], h3 = h4[3];
    const float4 h5 = h4[4], h6 = h4[5], h7 = h4[6], h8 = h4[7];
    float a = 0.f;
    a = fmaf(q0.x, h0.x, a); a = fmaf(q0.y, h0.y, a); a = fmaf(q0.z, h0.z, a); a = fmaf(q0.w, h0.w, a);
    a = fmaf(q1.x, h1.x, a); a = fmaf(q1.y, h1.y, a); a = fmaf(q1.z, h1.z, a); a = fmaf(q1.w, h1.w, a);
    a = fmaf(q2.x, h2.x, a); a = fmaf(q2.y, h2.y, a); a = fmaf(q2.z, h2.z, a); a = fmaf(q2.w, h2.w, a);
    a = fmaf(q3.x, h3.x, a); a = fmaf(q3.y, h3.y, a); a = fmaf(q3.z, h3.z, a); a = fmaf(q3.w, h3.w, a);
    a = fmaf(q4.x, h5.x, a); a = fmaf(q4.y, h5.y, a); a = fmaf(q4.z, h5.z, a); a = fmaf(q4.w, h5.w, a);
    a = fmaf(q5.x, h6.x, a); a = fmaf(q5.y, h6.y, a); a = fmaf(q5.z, h6.z, a); a = fmaf(q5.w, h6.w, a);
    a = fmaf(q6.x, h7.x, a); a = fmaf(q6.y, h7.y, a); a = fmaf(q6.z, h7.z, a); a = fmaf(q6.w, h7.w, a);
    a = fmaf(q7.x, h8.x, a); a = fmaf(q7.y, h8.y, a); a = fmaf(q7.z, h8.z, a); a = fmaf(q7.w, h8.w, a);
    a += __shfl_xor(a, 1);
    a += __shfl_xor(a, 2);
    a += __shfl_xor(a, 4);
    // kc==0 roots: add xproj and apply this gate's activation in parallel
    if (kc == 0) {
      a += xv;
      const float sg = 1.f / (1.f + __expf(-a));
      const float th = 1.f - 2.f / (1.f + __expf(2.f * a));
      a = (gate == 2) ? th : sg;
    }
    // gather the 4 ACTIVATED gates of this wave's two elements to lanes 0/32
    const float gi = __shfl(a, base + 0);
    const float gf = __shfl(a, base + 8);
    const float gg = __shfl(a, base + 16);
    const float go = __shfl(a, base + 24);
    if (isprod) {
      c = gf * c + gi * gg;
      const float hv = go * (1.f - 2.f / (1.f + __expf(2.f * c)));
      const unsigned long long word =
          ((unsigned long long)(stampbase + t + 1) << 32) | __float_as_uint(hv);
      // single agent store (fire-and-forget; ack floats across naked barrier)
      __hip_atomic_store(&ex[(size_t)t * 512 + dir * 256 + he], word,
                         __ATOMIC_RELAXED, __HIP_MEMORY_SCOPE_AGENT);
      hs[p ^ 1][poff] = hv;  // self-stage own element
      const int rowt = dir ? (Tn - 1 - t) : t;
      hcat[(size_t)rowt * 512 + dir * 256 + he] = hv;  // fire-and-forget
    } else if (ispoll && t + 1 < Tn) {
      const unsigned long long* pp = &ex[(size_t)t * 512 + dir * 256 + s0];
      const unsigned tgt = stampbase + (unsigned)t + 1u;
      typedef unsigned int u32x4 __attribute__((ext_vector_type(4)));
      u32x4 va, vb;
      int tot = 0;
      asm volatile("s_sleep 9");    // ~240ns: probe service centered on visibility
      for (;;) {
        // two pipelined 16B probes, one wait: 4 slots per round trip
        asm volatile("global_load_dwordx4 %0, %2, off sc0 sc1\n\t"
                     "global_load_dwordx4 %1, %2, off offset:16 sc0 sc1\n\t"
                     "s_waitcnt vmcnt(0)"
                     : "=v"(va), "=v"(vb) : "v"(pp) : "memory");
        if (va.y == tgt && va.w == tgt && vb.y == tgt && vb.w == tgt) break;
        if (++tot >= (1 << 18)) break;
        asm volatile("s_sleep 3");  // ~80ns pacing between probes
      }
      float4 hv4;
      hv4.x = __uint_as_float(va.x);
      hv4.y = __uint_as_float(va.z);
      hv4.z = __uint_as_float(vb.x);
      hv4.w = __uint_as_float(vb.z);
      *(float4*)&hs[p ^ 1][coff4] = hv4;
    }
    if (kc == 0 && t + 1 < Tn)  // xv prefetch AFTER poll; floats across barrier
      xv = xpD[(size_t)(dir ? (Tn - 2 - t) : (t + 1)) * 2048 + gr];
    // naked barrier: LDS ordering only, no vmcnt drain
    asm volatile("s_waitcnt lgkmcnt(0)\n\ts_barrier" ::: "memory");
  }
}

// ---- final 1024->7 matmul + softmax per timestep ----
__global__ __launch_bounds__(64) void mlp2_k(const float* __restrict__ h1,
                                             const float* __restrict__ w2,
                                             const float* __restrict__ b2,
                                             float* __restrict__ out) {
  __shared__ float hrow[1024];
  __shared__ float lg[8];
  const int t = blockIdx.x, tid = threadIdx.x;
  for (int i = tid; i < 1024; i += 64) hrow[i] = h1[(size_t)t * 1024 + i];
  __syncthreads();
  const int o = tid >> 3, kc = tid & 7;
  float acc = 0.f;
  if (o < 7) {
    const float* wv = w2 + (size_t)o * 1024 + kc * 128;
    const float* h = &hrow[kc * 128];
    for (int jj = 0; jj < 128; jj++) acc = fmaf(wv[jj], h[jj], acc);
  }
#pragma unroll
  for (int off = 1; off < 8; off <<= 1) acc += __shfl_xor(acc, off);
  if (o < 7 && kc == 0) lg[o] = acc + b2[o];
  __syncthreads();
  if (tid == 0) {
    float mx = -1e30f;
#pragma unroll
    for (int i = 0; i < 7; i++) mx = fmaxf(mx, lg[i]);
    float e[7];
    float s = 0.f;
#pragma unroll
    for (int i = 0; i < 7; i++) { e[i] = __expf(lg[i] - mx); s += e[i]; }
    const float inv = 1.f / s;
#pragma unroll
    for (int i = 0; i < 7; i++) out[t * 7 + i] = e[i] * inv;
  }
}

extern "C" void kernel_launch(void* const* d_in, const int* in_sizes, int n_in,
                              void* d_out, int out_size, void* d_ws, size_t ws_size,
                              hipStream_t stream) {
  const int* ids = (const int*)d_in[0];
  const float* tab = (const float*)d_in[1];
  const float* wih = (const float*)d_in[2];   // (2,2,1024,512)
  const float* whh = (const float*)d_in[3];   // (2,2,1024,256)
  const float* bih = (const float*)d_in[4];   // (2,2,1024)
  const float* bhh = (const float*)d_in[5];
  const float* w1 = (const float*)d_in[6];    // (1024,512)
  const float* b1 = (const float*)d_in[7];
  const float* w2 = (const float*)d_in[8];    // (7,1024)
  const float* b2 = (const float*)d_in[9];
  float* out = (float*)d_out;                 // (200,7) f32
  float* ws = (float*)d_ws;

  float* xp = ws + 102400;            // 200*2048 (reused both layers)
  float* h0 = ws + 512000;            // 200*512
  float* h1 = ws + 614400;            // 200*512
  float* hm = ws + 716800;            // 200*1024
  unsigned long long* ex = (unsigned long long*)(ws + 921600);  // 200*512 slots

  // NO memset: layer stamp ranges are disjoint (t+1 vs 1e6+t+1) and each
  // layer rewrites all slots each launch -> no stale-stamp false positives
  // across graph replays; 0xAA poison on first call never matches either.
  // layer 0 (embed gather fused into the xproj gemm)
  gemm_rows<<<dim3(8, 25), 256, 0, stream>>>(nullptr, ids, tab, wih, bih, bhh, xp, 2048, 0);
  rec_k<<<128, 512, 0, stream>>>(xp, h0, ex, whh, 0u);
  // layer 1 (shared ex buffer, disjoint stamp base)
  gemm_rows<<<dim3(8, 25), 256, 0, stream>>>(h0, nullptr, nullptr, wih + 1048576,
                                             bih + 2048, bhh + 2048, xp, 2048, 0);
  rec_k<<<128, 512, 0, stream>>>(xp, h1, ex, whh + 524288, 1000000u);
  // MLP
  gemm_rows<<<dim3(4, 25), 256, 0, stream>>>(h1, nullptr, nullptr, w1, b1, nullptr, hm, 1024, 1);
  mlp2_k<<<Tn, 64, 0, stream>>>(hm, w2, b2, out);
}